// Round 12
// baseline (63.441 us; speedup 1.0000x reference)
//
#include <hip/hip_runtime.h>
#include <hip/hip_bf16.h>

typedef __attribute__((ext_vector_type(8))) short short8;   // 8 bf16 MFMA A/B frag
typedef __attribute__((ext_vector_type(4))) float fv4;      // MFMA C/D frag

constexpr int B_ = 16, A_ = 1024, V_ = 1024, D_ = 512;

__device__ __forceinline__ unsigned cvtpk(float lo, float hi) {
    unsigned r;
    asm("v_cvt_pk_bf16_f32 %0, %1, %2" : "=v"(r) : "v"(lo), "v"(hi));
    return r;
}
#define SB0() __builtin_amdgcn_sched_barrier(0)

struct Stage { fv4 x0, x1, x2, x3; };

// Fused: fp32 -> bf16 convert + row norms + 256x256 MFMA tile + sqrt epilogue.
// 512 threads = 8 waves (2M x 4N). BK=64, 8 K-tiles, double-buffered LDS.
// r4 schedule (best measured): ISSUE q0,q1 at iter top; PROC+ISSUE spread
// across phases; natural vmcnt=0 at the barrier (no exposed drain).
// r12 deltas: bv held live through phase 3 (no re-read); nontemporal C stores.
__global__ void __launch_bounds__(512, 2)
l2dist_fused256(const float* __restrict__ audio, const float* __restrict__ visual,
                float* __restrict__ out)
{
    __shared__ __align__(16) char sA[2 * 256 * 128];   // [buf][row 256][64 bf16]
    __shared__ __align__(16) char sB[2 * 256 * 128];
    __shared__ float lnrm[512];                        // [0..255]=A rows, [256..511]=V rows

    const int t = threadIdx.x, lane = t & 63, w = t >> 6;
    const int wm = w >> 2, wn = w & 3;                 // wave C-slab: 128 rows x 64 cols

    // XCD-bijective swizzle: 256 blocks; each XCD gets 32 = 2 whole batches.
    const int orig = blockIdx.x;
    const int wg   = (orig & 7) * 32 + (orig >> 3);
    const int b = wg >> 4, tile = wg & 15, ab = tile >> 2, vb = tile & 3;

    const float* Ag = audio  + ((size_t)b * A_ + ab * 256) * D_;
    const float* Vg = visual + ((size_t)b * V_ + vb * 256) * D_;

    // staging geometry: 4-lane quad per row; thread covers 16 floats of one row
    const int rg  = t >> 2;            // 0..127 row within half-panel
    const int lq  = t & 3;             // quad lane
    const int key = rg & 7;            // LDS chunk swizzle key

    const float* g0 = Ag + (size_t)rg * D_ + lq * 4;           // A rows 0-127
    const float* g1 = Ag + (size_t)(128 + rg) * D_ + lq * 4;   // A rows 128-255
    const float* g2 = Vg + (size_t)rg * D_ + lq * 4;           // V rows 0-127
    const float* g3 = Vg + (size_t)(128 + rg) * D_ + lq * 4;   // V rows 128-255

    const int oLo = rg * 128;                // LDS row byte offset, half 0
    const int oHi = (128 + rg) * 128;        // half 1

    float ps0 = 0.f, ps1 = 0.f, ps2 = 0.f, ps3 = 0.f;   // register norm partials

#define ISSUE(S, gbase, koff) do {                                   \
        const float* _p = (gbase) + (koff);                          \
        S.x0 = *(const fv4*)(_p);      S.x1 = *(const fv4*)(_p + 16);\
        S.x2 = *(const fv4*)(_p + 32); S.x3 = *(const fv4*)(_p + 48);\
    } while (0)

    // convert + fp32 norm partial + swizzled LDS write for one quarter
#define PROC(S, dst, rowoff, ps) do {                                            \
        ps += S.x0[0]*S.x0[0] + S.x0[1]*S.x0[1] + S.x0[2]*S.x0[2] + S.x0[3]*S.x0[3] \
            + S.x1[0]*S.x1[0] + S.x1[1]*S.x1[1] + S.x1[2]*S.x1[2] + S.x1[3]*S.x1[3] \
            + S.x2[0]*S.x2[0] + S.x2[1]*S.x2[1] + S.x2[2]*S.x2[2] + S.x2[3]*S.x2[3] \
            + S.x3[0]*S.x3[0] + S.x3[1]*S.x3[1] + S.x3[2]*S.x3[2] + S.x3[3]*S.x3[3];\
        char* _d = (dst) + (rowoff);                                             \
        { int2 _v; _v.x = (int)cvtpk(S.x0[0], S.x0[1]); _v.y = (int)cvtpk(S.x0[2], S.x0[3]); \
          *(int2*)(_d + ((((0 + (lq >> 1)) ^ key) << 4) + (lq & 1) * 8)) = _v; } \
        { int2 _v; _v.x = (int)cvtpk(S.x1[0], S.x1[1]); _v.y = (int)cvtpk(S.x1[2], S.x1[3]); \
          *(int2*)(_d + ((((2 + (lq >> 1)) ^ key) << 4) + (lq & 1) * 8)) = _v; } \
        { int2 _v; _v.x = (int)cvtpk(S.x2[0], S.x2[1]); _v.y = (int)cvtpk(S.x2[2], S.x2[3]); \
          *(int2*)(_d + ((((4 + (lq >> 1)) ^ key) << 4) + (lq & 1) * 8)) = _v; } \
        { int2 _v; _v.x = (int)cvtpk(S.x3[0], S.x3[1]); _v.y = (int)cvtpk(S.x3[2], S.x3[3]); \
          *(int2*)(_d + ((((6 + (lq >> 1)) ^ key) << 4) + (lq & 1) * 8)) = _v; } \
    } while (0)

    // ---- prologue: stage K-tile 0 into buf 0 ----
    {
        Stage p0, p1, p2, p3;
        ISSUE(p0, g0, 0); ISSUE(p1, g1, 0); ISSUE(p2, g2, 0); ISSUE(p3, g3, 0); SB0();
        PROC(p0, sA, oLo, ps0);
        PROC(p1, sA, oHi, ps1);
        PROC(p2, sB, oLo, ps2);
        PROC(p3, sB, oHi, ps3);
    }
    __syncthreads();

    fv4 acc[8][4];
#pragma unroll
    for (int m = 0; m < 8; ++m)
#pragma unroll
        for (int n = 0; n < 4; ++n) acc[m][n] = fv4{0.f, 0.f, 0.f, 0.f};

    const int frow = lane & 15, fg = lane >> 4, xk = frow & 7;
    const int cof0 = ((0 + fg) ^ xk) << 4;    // k-half 0 swizzled chunk
    const int cof1 = ((4 + fg) ^ xk) << 4;    // k-half 1

#pragma unroll 1
    for (int kt = 0; kt < 8; ++kt) {
        const int cur = kt & 1;
        char* dstA = sA + (cur ^ 1) * 32768;
        char* dstB = sB + (cur ^ 1) * 32768;
        const char* Ab = sA + cur * 32768 + (wm * 128 + frow) * 128;
        const char* Bb = sB + cur * 32768 + (wn * 64 + frow) * 128;
        const int koff = (kt + 1) * 64;
        const bool st = (kt < 7);

        Stage q0, q1, q2, q3;
        if (st) { ISSUE(q0, g0, koff); ISSUE(q1, g1, koff); SB0(); }

        short8 av[4][2];
        short8 bv[2][2];     // B n0-1: live through phase 3 (no re-read)
        short8 bv2[2][2];    // B n2-3
        // ---- phase 0: A m0-3 (8 reads) + B n0-1 (4 reads); 16 MFMA ----
        {
#pragma unroll
            for (int m = 0; m < 4; ++m) {
                av[m][0] = *(const short8*)(Ab + m * 2048 + cof0);
                av[m][1] = *(const short8*)(Ab + m * 2048 + cof1);
            }
#pragma unroll
            for (int n = 0; n < 2; ++n) {
                bv[n][0] = *(const short8*)(Bb + n * 2048 + cof0);
                bv[n][1] = *(const short8*)(Bb + n * 2048 + cof1);
            }
            __builtin_amdgcn_s_setprio(1);
#pragma unroll
            for (int k = 0; k < 2; ++k)
#pragma unroll
                for (int m = 0; m < 4; ++m)
#pragma unroll
                    for (int n = 0; n < 2; ++n)
                        acc[m][n] = __builtin_amdgcn_mfma_f32_16x16x32_bf16(av[m][k], bv[n][k], acc[m][n], 0, 0, 0);
            __builtin_amdgcn_s_setprio(0);
        }
        if (st) { PROC(q0, dstA, oLo, ps0); ISSUE(q2, g2, koff); SB0(); }

        // ---- phase 1: B n2-3 (4 reads); 16 MFMA (reuse av) ----
        {
#pragma unroll
            for (int n = 0; n < 2; ++n) {
                bv2[n][0] = *(const short8*)(Bb + (n + 2) * 2048 + cof0);
                bv2[n][1] = *(const short8*)(Bb + (n + 2) * 2048 + cof1);
            }
            __builtin_amdgcn_s_setprio(1);
#pragma unroll
            for (int k = 0; k < 2; ++k)
#pragma unroll
                for (int m = 0; m < 4; ++m)
#pragma unroll
                    for (int n = 0; n < 2; ++n)
                        acc[m][n + 2] = __builtin_amdgcn_mfma_f32_16x16x32_bf16(av[m][k], bv2[n][k], acc[m][n + 2], 0, 0, 0);
            __builtin_amdgcn_s_setprio(0);
        }
        if (st) { PROC(q1, dstA, oHi, ps1); ISSUE(q3, g3, koff); SB0(); }

        // ---- phase 2: A m4-7 (8 reads, overwrite av); 16 MFMA (reuse bv2) ----
        {
#pragma unroll
            for (int m = 0; m < 4; ++m) {
                av[m][0] = *(const short8*)(Ab + (m + 4) * 2048 + cof0);
                av[m][1] = *(const short8*)(Ab + (m + 4) * 2048 + cof1);
            }
            __builtin_amdgcn_s_setprio(1);
#pragma unroll
            for (int k = 0; k < 2; ++k)
#pragma unroll
                for (int m = 0; m < 4; ++m)
#pragma unroll
                    for (int n = 0; n < 2; ++n)
                        acc[m + 4][n + 2] = __builtin_amdgcn_mfma_f32_16x16x32_bf16(av[m][k], bv2[n][k], acc[m + 4][n + 2], 0, 0, 0);
            __builtin_amdgcn_s_setprio(0);
        }
        if (st) PROC(q2, dstB, oLo, ps2);

        // ---- phase 3: no reads; 16 MFMA (reuse av m4-7 and LIVE bv n0-1) ----
        {
            __builtin_amdgcn_s_setprio(1);
#pragma unroll
            for (int k = 0; k < 2; ++k)
#pragma unroll
                for (int m = 0; m < 4; ++m)
#pragma unroll
                    for (int n = 0; n < 2; ++n)
                        acc[m + 4][n] = __builtin_amdgcn_mfma_f32_16x16x32_bf16(av[m][k], bv[n][k], acc[m + 4][n], 0, 0, 0);
            __builtin_amdgcn_s_setprio(0);
        }
        if (st) PROC(q3, dstB, oHi, ps3);

        __syncthreads();   // writes to buf^1 committed; reads of buf done
    }

    // ---- norm reduce: quad shuffle + single LDS write ----
    ps0 += __shfl_xor(ps0, 1, 64); ps0 += __shfl_xor(ps0, 2, 64);
    ps1 += __shfl_xor(ps1, 1, 64); ps1 += __shfl_xor(ps1, 2, 64);
    ps2 += __shfl_xor(ps2, 1, 64); ps2 += __shfl_xor(ps2, 2, 64);
    ps3 += __shfl_xor(ps3, 1, 64); ps3 += __shfl_xor(ps3, 2, 64);
    if (lq == 0) {
        lnrm[rg]       = ps0;
        lnrm[128 + rg] = ps1;
        lnrm[256 + rg] = ps2;
        lnrm[384 + rg] = ps3;
    }
    __syncthreads();

    // ---- fused epilogue: out = sqrt(max(||a||^2 + ||v||^2 - 2*cross, 0)) ----
    float* Ob = out + (size_t)b * A_ * V_ + (size_t)(ab * 256) * V_ + vb * 256;
#pragma unroll
    for (int m = 0; m < 8; ++m) {
#pragma unroll
        for (int n = 0; n < 4; ++n) {
            const int col = wn * 64 + n * 16 + frow;      // C/D: col = lane&15
            const float vsq = lnrm[256 + col];
#pragma unroll
            for (int j = 0; j < 4; ++j) {
                const int row = wm * 128 + m * 16 + fg * 4 + j;   // row=(lane>>4)*4+reg
                float d2 = lnrm[row] + vsq - 2.f * acc[m][n][j];
                __builtin_nontemporal_store(sqrtf(fmaxf(d2, 0.f)),
                                            &Ob[(size_t)row * V_ + col]);
            }
        }
    }
#undef ISSUE
#undef PROC
}

extern "C" void kernel_launch(void* const* d_in, const int* in_sizes, int n_in,
                              void* d_out, int out_size, void* d_ws, size_t ws_size,
                              hipStream_t stream) {
    const float* audio  = (const float*)d_in[0];
    const float* visual = (const float*)d_in[1];
    float* out = (float*)d_out;
    l2dist_fused256<<<256, 512, 0, stream>>>(audio, visual, out);
}